// Round 1
// baseline (135.741 us; speedup 1.0000x reference)
//
#include <hip/hip_runtime.h>
#include <math.h>

constexpr int Bn = 64;
constexpr int Dn = 1024;
constexpr int KCn = 8;                       // k-chunks for Bsum partials
constexpr float LOG2E = 1.4426950408889634f;
constexpr float LN2   = 0.6931471805599453f;

__device__ __forceinline__ float exp2_fast(float v) {
#if defined(__has_builtin)
#if __has_builtin(__builtin_amdgcn_exp2f)
  return __builtin_amdgcn_exp2f(v);
#else
  return exp2f(v);
#endif
#else
  return exp2f(v);
#endif
}

// ---------------------------------------------------------------------------
// K1: Bpart[b][kc][j] = sum_{k in chunk kc} |x[b][j] - x[b][k]|
// grid = Bn * 4(jc) * KCn(kc) = 2048 blocks, 256 threads (thread = one j)
// ---------------------------------------------------------------------------
__global__ __launch_bounds__(256) void k1_bsum(const float* __restrict__ x,
                                               float* __restrict__ Bpart) {
  int blk = blockIdx.x;
  int kc = blk & (KCn - 1);        // bits 0..2
  int jc = (blk >> 3) & 3;         // bits 3..4
  int b  = blk >> 5;               // bits 5..10
  __shared__ float xk[128];
  int tid = threadIdx.x;
  if (tid < 128) xk[tid] = x[b * Dn + kc * 128 + tid];
  __syncthreads();
  int j = jc * 256 + tid;
  float xj = x[b * Dn + j];
  float acc = 0.f;
#pragma unroll 16
  for (int k = 0; k < 128; ++k) acc += fabsf(xj - xk[k]);
  Bpart[(b * KCn + kc) * Dn + j] = acc;
}

// ---------------------------------------------------------------------------
// K2: xs[b,i] = sum_j softmax_j( scaling[i]*x[b,j] - Bsum[b,j] ) * x[b,j]
// One wave per row, 16 rows per wave. Row data (x*log2e, -Bsum*log2e) lives
// entirely in registers (16 elems/lane). grid = Bn*16 = 1024 blocks of 256.
// ---------------------------------------------------------------------------
__global__ __launch_bounds__(256, 4) void k2_softsort(
    const float* __restrict__ x, const float* __restrict__ Bpart,
    float* __restrict__ xs_out) {
  int b     = blockIdx.x >> 4;
  int chunk = blockIdx.x & 15;
  int tid  = threadIdx.x;
  int wave = tid >> 6;
  int lane = tid & 63;
  int j0 = lane << 4;              // lane owns elements [j0, j0+16)

  float av[16], cv[16];
  {
    const float4* xb = (const float4*)(x + b * Dn + j0);
#pragma unroll
    for (int u = 0; u < 4; ++u) {
      float4 v = xb[u];
      av[4*u+0] = v.x * LOG2E; av[4*u+1] = v.y * LOG2E;
      av[4*u+2] = v.z * LOG2E; av[4*u+3] = v.w * LOG2E;
    }
  }
  {
    float bs[16];
#pragma unroll
    for (int t = 0; t < 16; ++t) bs[t] = 0.f;
#pragma unroll
    for (int kc = 0; kc < KCn; ++kc) {
      const float4* bp = (const float4*)(Bpart + (b * KCn + kc) * Dn + j0);
#pragma unroll
      for (int u = 0; u < 4; ++u) {
        float4 v = bp[u];
        bs[4*u+0] += v.x; bs[4*u+1] += v.y;
        bs[4*u+2] += v.z; bs[4*u+3] += v.w;
      }
    }
#pragma unroll
    for (int t = 0; t < 16; ++t) cv[t] = -bs[t] * LOG2E;
  }

  int i0 = chunk * 64 + wave * 16;
  for (int r = 0; r < 16; ++r) {
    int i = i0 + r;
    float sc = (float)(Dn - 1 - 2 * i);   // scaling[i], exact in fp32
    float tv[16];
    float m = -3.4e38f;
#pragma unroll
    for (int t = 0; t < 16; ++t) {
      tv[t] = fmaf(sc, av[t], cv[t]);     // logit * log2e
      m = fmaxf(m, tv[t]);
    }
#pragma unroll
    for (int o = 32; o >= 1; o >>= 1) m = fmaxf(m, __shfl_xor(m, o, 64));
    float se = 0.f, sd = 0.f;
#pragma unroll
    for (int t = 0; t < 16; ++t) {
      float e = exp2_fast(tv[t] - m);
      se += e;
      sd = fmaf(e, av[t], sd);            // accumulates e * x * log2e
    }
#pragma unroll
    for (int o = 32; o >= 1; o >>= 1) {
      se += __shfl_xor(se, o, 64);
      sd += __shfl_xor(sd, o, 64);
    }
    if (lane == 0)
      xs_out[b * Dn + i] = sd * __builtin_amdgcn_rcpf(se) * LN2;
  }
}

// ---------------------------------------------------------------------------
// K3/K4: h = leaky(in @ W^T + bias).  Block = 16 batches x 16 cols, full K.
// Activation tile in LDS with +4-per-row rotation to kill the stride-4096
// bank conflict (2-way residual conflict = free).  grid = 4*64 = 256 blocks.
// TAIL: fuse layer 3 (out2[b,o] += h*W3[o,n], block-reduced, atomicAdd).
// ---------------------------------------------------------------------------
template <bool TAIL>
__global__ __launch_bounds__(256) void layer_kernel(
    const float* __restrict__ in, const float* __restrict__ W,
    const float* __restrict__ bias, float* __restrict__ out,
    const float* __restrict__ W3, const float* __restrict__ b3,
    float* __restrict__ out2) {
  __shared__ float s[16][Dn];              // 64 KiB
  int bc = blockIdx.x >> 6;                // batch chunk 0..3
  int nc = blockIdx.x & 63;                // col chunk 0..63
  int tid = threadIdx.x;
  const float* src = in + bc * 16 * Dn;
#pragma unroll
  for (int u = 0; u < 16; ++u) {           // 4096 float4s / 256 threads
    int idx = (u * 256 + tid) << 2;        // element index, multiple of 4
    int row = idx >> 10;
    int k   = idx & 1023;
    float4 v = *(const float4*)(src + idx);
    *(float4*)&s[row][(k + 4 * row) & 1023] = v;
  }
  __syncthreads();

  int bl = tid & 15;                       // local batch
  int nl = tid >> 4;                       // local col
  int n = nc * 16 + nl;
  const float* wrow = W + n * Dn;
  float acc = 0.f;
  int p = bl << 2;                         // rotated start position
#pragma unroll 4
  for (int k0 = 0; k0 < Dn; k0 += 4) {
    float4 a = *(const float4*)&s[bl][p];  // element k0 of row bl
    float4 w = *(const float4*)(wrow + k0);
    acc = fmaf(a.x, w.x, acc);
    acc = fmaf(a.y, w.y, acc);
    acc = fmaf(a.z, w.z, acc);
    acc = fmaf(a.w, w.w, acc);
    p = (p + 4) & 1023;
  }
  float h = acc + bias[n];
  h = h >= 0.f ? h : 0.01f * h;

  if (!TAIL) {
    out[(bc * 16 + bl) * Dn + n] = h;
  } else {
    float p0 = h * W3[n];
    float p1 = h * W3[Dn + n];
    __syncthreads();                       // everyone done reading s
    float* red = &s[0][0];
    red[(bl * 16 + nl) * 2 + 0] = p0;
    red[(bl * 16 + nl) * 2 + 1] = p1;
    __syncthreads();
    if (tid < 32) {
      int o  = tid & 1;
      int bb = tid >> 1;
      float t = 0.f;
#pragma unroll
      for (int q = 0; q < 16; ++q) t += red[(bb * 16 + q) * 2 + o];
      if (nc == 0) t += b3[o];
      atomicAdd(out2 + (bc * 16 + bb) * 2 + o, t);
    }
  }
}

extern "C" void kernel_launch(void* const* d_in, const int* in_sizes, int n_in,
                              void* d_out, int out_size, void* d_ws, size_t ws_size,
                              hipStream_t stream) {
  const float* x  = (const float*)d_in[0];
  const float* W1 = (const float*)d_in[1];
  const float* b1 = (const float*)d_in[2];
  const float* W2 = (const float*)d_in[3];
  const float* b2 = (const float*)d_in[4];
  const float* W3 = (const float*)d_in[5];
  const float* b3 = (const float*)d_in[6];
  float* out = (float*)d_out;
  float* ws = (float*)d_ws;

  float* Bpart = ws;                        // 64*8*1024 = 2 MiB
  float* xs    = Bpart + Bn * KCn * Dn;     // 64*1024
  float* h1    = xs + Bn * Dn;              // 64*1024

  hipMemsetAsync(d_out, 0, Bn * 2 * sizeof(float), stream);  // atomics target
  k1_bsum<<<Bn * 4 * KCn, 256, 0, stream>>>(x, Bpart);
  k2_softsort<<<Bn * 16, 256, 0, stream>>>(x, Bpart, xs);
  layer_kernel<false><<<256, 256, 0, stream>>>(xs, W1, b1, h1,
                                               nullptr, nullptr, nullptr);
  layer_kernel<true><<<256, 256, 0, stream>>>(h1, W2, b2, nullptr,
                                              W3, b3, out);
}

// Round 2
// 134.320 us; speedup vs baseline: 1.0106x; 1.0106x over previous
//
#include <hip/hip_runtime.h>
#include <math.h>

constexpr int Bn = 64;
constexpr int Dn = 1024;
constexpr int KCn = 8;                       // k-chunks for Bsum partials
constexpr float LOG2E = 1.4426950408889634f;
constexpr float LN2   = 0.6931471805599453f;

__device__ __forceinline__ float exp2_fast(float v) {
#if defined(__has_builtin)
#if __has_builtin(__builtin_amdgcn_exp2f)
  return __builtin_amdgcn_exp2f(v);
#else
  return exp2f(v);
#endif
#else
  return exp2f(v);
#endif
}

// ---------------------------------------------------------------------------
// K1: Bpart[b][kc][j] = sum_{k in chunk kc} |x[b][j] - x[b][k]|
// grid = Bn*4*KCn = 2048 blocks, 256 threads (thread = one j)
// ---------------------------------------------------------------------------
__global__ __launch_bounds__(256) void k1_bsum(const float* __restrict__ x,
                                               float* __restrict__ Bpart) {
  int blk = blockIdx.x;
  int kc = blk & (KCn - 1);
  int jc = (blk >> 3) & 3;
  int b  = blk >> 5;
  __shared__ float xk[128];
  int tid = threadIdx.x;
  if (tid < 128) xk[tid] = x[b * Dn + kc * 128 + tid];
  __syncthreads();
  int j = jc * 256 + tid;
  float xj = x[b * Dn + j];
  float a0 = 0.f, a1 = 0.f, a2 = 0.f, a3 = 0.f;
#pragma unroll 8
  for (int k = 0; k < 128; k += 4) {
    a0 += fabsf(xj - xk[k + 0]);
    a1 += fabsf(xj - xk[k + 1]);
    a2 += fabsf(xj - xk[k + 2]);
    a3 += fabsf(xj - xk[k + 3]);
  }
  Bpart[(b * KCn + kc) * Dn + j] = (a0 + a1) + (a2 + a3);
}

// ---------------------------------------------------------------------------
// K1b: pairs[b][j] = ( x*log2e , -Bsum*log2e ).  Also zeroes d_out (128 f32).
// grid = 256 blocks of 256 (blk = b*4 + jc)
// ---------------------------------------------------------------------------
__global__ __launch_bounds__(256) void k1b_pairs(
    const float* __restrict__ x, const float* __restrict__ Bpart,
    float2* __restrict__ pairs, float* __restrict__ out) {
  int blk = blockIdx.x;
  int jc = blk & 3;
  int b  = blk >> 2;
  int j = jc * 256 + threadIdx.x;
  float s = 0.f;
#pragma unroll
  for (int kc = 0; kc < KCn; ++kc) s += Bpart[(b * KCn + kc) * Dn + j];
  float a = x[b * Dn + j] * LOG2E;
  pairs[b * Dn + j] = make_float2(a, -s * LOG2E);
  if (blk == 0 && threadIdx.x < 128) out[threadIdx.x] = 0.f;
}

// ---------------------------------------------------------------------------
// K2: xs[b,i] = sum_j softmax_j(sc_i*x_j - Bsum_j) * x_j, in exp2 domain.
// Lane <-> row: block = 64 rows of one b (one row per lane); 4 waves each own
// a 256-j quarter of wave-uniform (a,c) pairs (scalar loads, no shuffles).
// Wave-voted exp skip: groups with all t < m-44 contribute < 2^-44 rel.
// grid = Bn*16 = 1024 blocks of 256.
// ---------------------------------------------------------------------------
__global__ __launch_bounds__(256, 4) void k2_softsort(
    const float2* __restrict__ pairs, float* __restrict__ xs_out) {
  __shared__ float redM[4][64];
  __shared__ float redE[4][64];
  __shared__ float redD[4][64];
  int b  = blockIdx.x >> 4;
  int rc = blockIdx.x & 15;
  int tid  = threadIdx.x;
  int w    = __builtin_amdgcn_readfirstlane(tid >> 6);
  int lane = tid & 63;
  int i = rc * 64 + lane;
  float sc = (float)(Dn - 1 - 2 * i);   // exact in fp32
  const float2* pc = pairs + b * Dn + w * 256;   // wave-uniform base

  // ---- pass 1: this wave's local max over its 256 j ----
  float mv0 = -3.4e38f, mv1 = -3.4e38f, mv2 = -3.4e38f, mv3 = -3.4e38f;
  for (int g = 0; g < 256; g += 8) {
#pragma unroll
    for (int u = 0; u < 8; u += 4) {
      float2 v0 = pc[g + u + 0];
      float2 v1 = pc[g + u + 1];
      float2 v2 = pc[g + u + 2];
      float2 v3 = pc[g + u + 3];
      mv0 = fmaxf(mv0, fmaf(sc, v0.x, v0.y));
      mv1 = fmaxf(mv1, fmaf(sc, v1.x, v1.y));
      mv2 = fmaxf(mv2, fmaf(sc, v2.x, v2.y));
      mv3 = fmaxf(mv3, fmaf(sc, v3.x, v3.y));
    }
  }
  redM[w][lane] = fmaxf(fmaxf(mv0, mv1), fmaxf(mv2, mv3));
  __syncthreads();
  float mAll = fmaxf(fmaxf(redM[0][lane], redM[1][lane]),
                     fmaxf(redM[2][lane], redM[3][lane]));
  float thresh = mAll - 44.f;

  // ---- pass 2: exp-sum with wave-voted skip ----
  float se = 0.f, sd = 0.f;
  for (int g = 0; g < 256; g += 8) {
    float t[8], av[8];
#pragma unroll
    for (int u = 0; u < 8; ++u) {
      float2 v = pc[g + u];
      av[u] = v.x;
      t[u] = fmaf(sc, v.x, v.y);
    }
    float gm = fmaxf(fmaxf(fmaxf(t[0], t[1]), fmaxf(t[2], t[3])),
                     fmaxf(fmaxf(t[4], t[5]), fmaxf(t[6], t[7])));
    if (__any(gm > thresh)) {
#pragma unroll
      for (int u = 0; u < 8; ++u) {
        float e = exp2_fast(t[u] - mAll);
        se += e;
        sd = fmaf(e, av[u], sd);          // accumulates e * x * log2e
      }
    }
  }
  redE[w][lane] = se;
  redD[w][lane] = sd;
  __syncthreads();
  if (tid < 64) {
    float SE = (redE[0][lane] + redE[1][lane]) + (redE[2][lane] + redE[3][lane]);
    float SD = (redD[0][lane] + redD[1][lane]) + (redD[2][lane] + redD[3][lane]);
    xs_out[b * Dn + rc * 64 + lane] = SD / SE * LN2;
  }
}

// ---------------------------------------------------------------------------
// K3/K4: h = leaky(in @ W^T + bias).  Block = 8 batches x 16 cols, 2-way
// K-split.  LDS 32 KiB, grid = 8*64 = 512 blocks (~8 waves/CU).
// TAIL fuses layer 3 into atomicAdds on d_out (zeroed by k1b).
// ---------------------------------------------------------------------------
template <bool TAIL>
__global__ __launch_bounds__(256) void layer_kernel(
    const float* __restrict__ in, const float* __restrict__ W,
    const float* __restrict__ bias, float* __restrict__ out,
    const float* __restrict__ W3, const float* __restrict__ b3,
    float* __restrict__ out2) {
  __shared__ float s[8][Dn];               // 32 KiB
  __shared__ float red[128][2];
  int bc = blockIdx.x >> 6;                // batch chunk 0..7
  int nc = blockIdx.x & 63;                // col chunk 0..63
  int tid = threadIdx.x;
  const float* src = in + bc * 8 * Dn;
#pragma unroll
  for (int u = 0; u < 8; ++u) {            // 2048 float4s / 256 threads
    int idx = (u * 256 + tid) << 2;
    *(float4*)&s[idx >> 10][idx & 1023] = *(const float4*)(src + idx);
  }
  __syncthreads();

  int bl = tid & 7;                        // local batch 0..7
  int nl = (tid >> 3) & 15;                // local col 0..15
  int kc = tid >> 7;                       // K half 0..1
  int n = nc * 16 + nl;
  const float* wrow = W + n * Dn + kc * 512;
  const float* srow = &s[bl][kc * 512];
  float acc = 0.f;
#pragma unroll 4
  for (int k0 = 0; k0 < 512; k0 += 4) {
    float4 a = *(const float4*)(srow + k0);
    float4 ww = *(const float4*)(wrow + k0);
    acc = fmaf(a.x, ww.x, acc);
    acc = fmaf(a.y, ww.y, acc);
    acc = fmaf(a.z, ww.z, acc);
    acc = fmaf(a.w, ww.w, acc);
  }
  red[bl * 16 + nl][kc] = acc;
  __syncthreads();

  if (!TAIL) {
    if (tid < 128) {
      int bl2 = tid >> 4, nl2 = tid & 15;
      int n2 = nc * 16 + nl2;
      float h = red[tid][0] + red[tid][1] + bias[n2];
      h = h >= 0.f ? h : 0.01f * h;
      out[(bc * 8 + bl2) * Dn + n2] = h;
    }
  } else {
    float p0 = 0.f, p1 = 0.f;
    if (tid < 128) {
      int nl2 = tid & 15;
      int n2 = nc * 16 + nl2;
      float h = red[tid][0] + red[tid][1] + bias[n2];
      h = h >= 0.f ? h : 0.01f * h;
      p0 = h * W3[n2];
      p1 = h * W3[Dn + n2];
    }
    __syncthreads();
    if (tid < 128) { red[tid][0] = p0; red[tid][1] = p1; }
    __syncthreads();
    if (tid < 16) {
      int bl2 = tid >> 1, o = tid & 1;
      float t = 0.f;
#pragma unroll
      for (int q = 0; q < 16; ++q) t += red[bl2 * 16 + q][o];
      if (nc == 0) t += b3[o];
      atomicAdd(out2 + (bc * 8 + bl2) * 2 + o, t);
    }
  }
}

extern "C" void kernel_launch(void* const* d_in, const int* in_sizes, int n_in,
                              void* d_out, int out_size, void* d_ws, size_t ws_size,
                              hipStream_t stream) {
  const float* x  = (const float*)d_in[0];
  const float* W1 = (const float*)d_in[1];
  const float* b1 = (const float*)d_in[2];
  const float* W2 = (const float*)d_in[3];
  const float* b2 = (const float*)d_in[4];
  const float* W3 = (const float*)d_in[5];
  const float* b3 = (const float*)d_in[6];
  float* out = (float*)d_out;
  float* ws = (float*)d_ws;

  float*  Bpart = ws;                          // 64*8*1024 f32 = 2 MiB
  float2* pairs = (float2*)(Bpart + Bn * KCn * Dn);   // 64*1024 float2
  float*  xs    = (float*)(pairs + Bn * Dn);   // 64*1024
  float*  h1    = xs + Bn * Dn;                // 64*1024

  k1_bsum<<<Bn * 4 * KCn, 256, 0, stream>>>(x, Bpart);
  k1b_pairs<<<Bn * 4, 256, 0, stream>>>(x, Bpart, pairs, out);
  k2_softsort<<<Bn * 16, 256, 0, stream>>>(pairs, xs);
  layer_kernel<false><<<512, 256, 0, stream>>>(xs, W1, b1, h1,
                                               nullptr, nullptr, nullptr);
  layer_kernel<true><<<512, 256, 0, stream>>>(h1, W2, b2, nullptr,
                                              W3, b3, out);
}

// Round 3
// 130.875 us; speedup vs baseline: 1.0372x; 1.0263x over previous
//
#include <hip/hip_runtime.h>
#include <math.h>

constexpr int Bn = 64;
constexpr int Dn = 1024;
constexpr int KC = 32;                        // k-chunks in k1
constexpr float LOG2E = 1.4426950408889634f;
constexpr float LN2   = 0.6931471805599453f;

__device__ __forceinline__ float exp2_fast(float v) {
#if defined(__has_builtin)
#if __has_builtin(__builtin_amdgcn_exp2f)
  return __builtin_amdgcn_exp2f(v);
#else
  return exp2f(v);
#endif
#else
  return exp2f(v);
#endif
}

// ---------------------------------------------------------------------------
// K1: Bpart[b][kc][j] = sum_{k in 32-chunk kc} |x[b][j]-x[b][k]|
// grid = 64*32 = 2048 blocks, 256 thr, 4 j/thread.  k-chunk read as uniform
// b128 broadcasts (8 per thread) -> LDS pipe ~96 cyc/wave; VALU-bound.
// ---------------------------------------------------------------------------
__global__ __launch_bounds__(256) void k1_bsum(const float* __restrict__ x,
                                               float* __restrict__ Bpart) {
  int kc = blockIdx.x & 31;
  int b  = blockIdx.x >> 5;
  __shared__ float xk[32];
  int tid = threadIdx.x;
  if (tid < 32) xk[tid] = x[b * Dn + kc * 32 + tid];
  __syncthreads();
  float xj[4], acc[4];
#pragma unroll
  for (int u = 0; u < 4; ++u) {
    xj[u] = x[b * Dn + u * 256 + tid];
    acc[u] = 0.f;
  }
#pragma unroll
  for (int kq = 0; kq < 8; ++kq) {
    float4 kv = *(const float4*)&xk[kq * 4];
#pragma unroll
    for (int u = 0; u < 4; ++u) {
      acc[u] += (fabsf(xj[u] - kv.x) + fabsf(xj[u] - kv.y)) +
                (fabsf(xj[u] - kv.z) + fabsf(xj[u] - kv.w));
    }
  }
#pragma unroll
  for (int u = 0; u < 4; ++u)
    Bpart[(b * KC + kc) * Dn + u * 256 + tid] = acc[u];
}

// ---------------------------------------------------------------------------
// K1b: pairs[b][j] = ( x*log2e , -Bsum*log2e ); zeroes d_out.
// grid = 256 blocks of 256.
// ---------------------------------------------------------------------------
__global__ __launch_bounds__(256) void k1b_pairs(
    const float* __restrict__ x, const float* __restrict__ Bpart,
    float2* __restrict__ pairs, float* __restrict__ out) {
  int jc = blockIdx.x & 3;
  int b  = blockIdx.x >> 2;
  int j = jc * 256 + threadIdx.x;
  float s = 0.f;
#pragma unroll
  for (int kc = 0; kc < KC; ++kc) s += Bpart[(b * KC + kc) * Dn + j];
  pairs[b * Dn + j] = make_float2(x[b * Dn + j] * LOG2E, -s * LOG2E);
  if (blockIdx.x == 0 && threadIdx.x < 128) out[threadIdx.x] = 0.f;
}

// ---------------------------------------------------------------------------
// K2: xs[b,i] = sum_j softmax_j(sc_i*x_j - Bsum_j) * x_j  (exp2 domain).
// Lane = row; 4 waves each own a 256-j quarter of wave-uniform (a,c) pairs
// (scalar s_load path, zero cross-lane traffic); block-merge via tiny LDS.
// grid = 64*16 = 1024 blocks of 256 (4 waves/SIMD).
// ---------------------------------------------------------------------------
__global__ __launch_bounds__(256, 4) void k2_softsort(
    const float2* __restrict__ pairs, float* __restrict__ xs_out) {
  __shared__ float redM[4][64];
  __shared__ float redE[4][64];
  __shared__ float redD[4][64];
  int b  = blockIdx.x >> 4;
  int rc = blockIdx.x & 15;
  int tid  = threadIdx.x;
  int w    = tid >> 6;
  int lane = tid & 63;
  int i = rc * 64 + lane;
  float sc = (float)(Dn - 1 - 2 * i);          // exact in fp32
  const float2* pc = pairs + b * Dn + w * 256; // wave-uniform base

  // pass 1: wave-local max over its 256 j
  float m0 = -3.4e38f, m1 = -3.4e38f, m2 = -3.4e38f, m3 = -3.4e38f;
  for (int g = 0; g < 256; g += 4) {
    float2 v0 = pc[g + 0], v1 = pc[g + 1], v2 = pc[g + 2], v3 = pc[g + 3];
    m0 = fmaxf(m0, fmaf(sc, v0.x, v0.y));
    m1 = fmaxf(m1, fmaf(sc, v1.x, v1.y));
    m2 = fmaxf(m2, fmaf(sc, v2.x, v2.y));
    m3 = fmaxf(m3, fmaf(sc, v3.x, v3.y));
  }
  redM[w][lane] = fmaxf(fmaxf(m0, m1), fmaxf(m2, m3));
  __syncthreads();
  float mAll = fmaxf(fmaxf(redM[0][lane], redM[1][lane]),
                     fmaxf(redM[2][lane], redM[3][lane]));

  // pass 2: exp-sum (t folded: one v_sub + one v_fma per j, each 1-SGPR)
  float se = 0.f, sd = 0.f;
  for (int g = 0; g < 256; g += 4) {
#pragma unroll
    for (int u = 0; u < 4; ++u) {
      float2 v = pc[g + u];
      float e = exp2_fast(fmaf(sc, v.x, v.y - mAll));
      se += e;
      sd = fmaf(e, v.x, sd);
    }
  }
  redE[w][lane] = se;
  redD[w][lane] = sd;
  __syncthreads();
  if (tid < 64) {
    float SE = (redE[0][lane] + redE[1][lane]) + (redE[2][lane] + redE[3][lane]);
    float SD = (redD[0][lane] + redD[1][lane]) + (redD[2][lane] + redD[3][lane]);
    xs_out[b * Dn + rc * 64 + lane] = SD / SE * LN2;
  }
}

// ---------------------------------------------------------------------------
// K3/K4: h = leaky(in @ W^T + bias).  Block = 8 batches x 16 cols.
// Thread tile = 1 batch x 4 cols x K/8: one b128 a-read feeds 16 fma
// (1 B/fma LDS); W addresses identical across the 8 batch-lanes -> coalesced.
// s padded to stride 1028 (+4 words/row) so the 8 bl-addresses spread banks.
// grid = 8*64 = 512 blocks.  TAIL fuses layer 3 into atomicAdds on d_out.
// ---------------------------------------------------------------------------
template <bool TAIL>
__global__ __launch_bounds__(256) void layer_kernel(
    const float* __restrict__ in, const float* __restrict__ W,
    const float* __restrict__ bias, float* __restrict__ out,
    const float* __restrict__ W3, const float* __restrict__ b3,
    float* __restrict__ out2) {
  __shared__ float s[8][Dn + 4];
  __shared__ float red[8][16][8];
  __shared__ float r2[8][16][2];
  int bc = blockIdx.x >> 6;
  int nc = blockIdx.x & 63;
  int tid = threadIdx.x;
  const float* src = in + bc * 8 * Dn;
#pragma unroll
  for (int u = 0; u < 8; ++u) {
    int idx = (u * 256 + tid) << 2;
    *(float4*)&s[idx >> 10][idx & 1023] = *(const float4*)(src + idx);
  }
  __syncthreads();

  int bl = tid & 7;
  int nq = (tid >> 3) & 3;
  int kc = tid >> 5;
  int n0 = nc * 16 + nq * 4;
  const float* a  = &s[bl][kc * 128];
  const float* w0 = W + (size_t)(n0 + 0) * Dn + kc * 128;
  const float* w1 = W + (size_t)(n0 + 1) * Dn + kc * 128;
  const float* w2 = W + (size_t)(n0 + 2) * Dn + kc * 128;
  const float* w3 = W + (size_t)(n0 + 3) * Dn + kc * 128;
  float a0 = 0.f, a1 = 0.f, a2 = 0.f, a3 = 0.f;
#pragma unroll 4
  for (int kq = 0; kq < 32; ++kq) {
    float4 av = *(const float4*)(a + kq * 4);
    float4 b0 = *(const float4*)(w0 + kq * 4);
    float4 b1 = *(const float4*)(w1 + kq * 4);
    float4 b2 = *(const float4*)(w2 + kq * 4);
    float4 b3v = *(const float4*)(w3 + kq * 4);
    a0 = fmaf(av.x, b0.x, fmaf(av.y, b0.y, fmaf(av.z, b0.z, fmaf(av.w, b0.w, a0))));
    a1 = fmaf(av.x, b1.x, fmaf(av.y, b1.y, fmaf(av.z, b1.z, fmaf(av.w, b1.w, a1))));
    a2 = fmaf(av.x, b2.x, fmaf(av.y, b2.y, fmaf(av.z, b2.z, fmaf(av.w, b2.w, a2))));
    a3 = fmaf(av.x, b3v.x, fmaf(av.y, b3v.y, fmaf(av.z, b3v.z, fmaf(av.w, b3v.w, a3))));
  }
  red[bl][nq * 4 + 0][kc] = a0;
  red[bl][nq * 4 + 1][kc] = a1;
  red[bl][nq * 4 + 2][kc] = a2;
  red[bl][nq * 4 + 3][kc] = a3;
  __syncthreads();

  if (!TAIL) {
    if (tid < 128) {
      int bl2 = tid >> 4, nl2 = tid & 15;
      int n2 = nc * 16 + nl2;
      float hs = 0.f;
#pragma unroll
      for (int q = 0; q < 8; ++q) hs += red[bl2][nl2][q];
      float h = hs + bias[n2];
      h = h >= 0.f ? h : 0.01f * h;
      out[(bc * 8 + bl2) * Dn + n2] = h;
    }
  } else {
    if (tid < 128) {
      int bl2 = tid >> 4, nl2 = tid & 15;
      int n2 = nc * 16 + nl2;
      float hs = 0.f;
#pragma unroll
      for (int q = 0; q < 8; ++q) hs += red[bl2][nl2][q];
      float h = hs + bias[n2];
      h = h >= 0.f ? h : 0.01f * h;
      r2[bl2][nl2][0] = h * W3[n2];
      r2[bl2][nl2][1] = h * W3[Dn + n2];
    }
    __syncthreads();
    if (tid < 16) {
      int bl2 = tid >> 1, o = tid & 1;
      float t = 0.f;
#pragma unroll
      for (int q = 0; q < 16; ++q) t += r2[bl2][q][o];
      if (nc == 0) t += b3[o];
      atomicAdd(out2 + (bc * 8 + bl2) * 2 + o, t);
    }
  }
}

extern "C" void kernel_launch(void* const* d_in, const int* in_sizes, int n_in,
                              void* d_out, int out_size, void* d_ws, size_t ws_size,
                              hipStream_t stream) {
  const float* x  = (const float*)d_in[0];
  const float* W1 = (const float*)d_in[1];
  const float* b1 = (const float*)d_in[2];
  const float* W2 = (const float*)d_in[3];
  const float* b2 = (const float*)d_in[4];
  const float* W3 = (const float*)d_in[5];
  const float* b3 = (const float*)d_in[6];
  float* out = (float*)d_out;
  float* ws = (float*)d_ws;

  float*  Bpart = ws;                               // 64*32*1024 f32 = 8 MiB
  float2* pairs = (float2*)(Bpart + Bn * KC * Dn);  // 64*1024 float2
  float*  xs    = (float*)(pairs + Bn * Dn);        // 64*1024
  float*  h1    = xs + Bn * Dn;                     // 64*1024

  k1_bsum<<<Bn * KC, 256, 0, stream>>>(x, Bpart);
  k1b_pairs<<<Bn * 4, 256, 0, stream>>>(x, Bpart, pairs, out);
  k2_softsort<<<Bn * 16, 256, 0, stream>>>(pairs, xs);
  layer_kernel<false><<<512, 256, 0, stream>>>(xs, W1, b1, h1,
                                               nullptr, nullptr, nullptr);
  layer_kernel<true><<<512, 256, 0, stream>>>(h1, W2, b2, nullptr,
                                              W3, b3, out);
}

// Round 4
// 124.656 us; speedup vs baseline: 1.0889x; 1.0499x over previous
//
#include <hip/hip_runtime.h>
#include <math.h>

constexpr int Bn = 64;
constexpr int Dn = 1024;
constexpr float LOG2E = 1.4426950408889634f;
constexpr float LN2   = 0.6931471805599453f;

__device__ __forceinline__ float exp2_fast(float v) {
#if defined(__has_builtin)
#if __has_builtin(__builtin_amdgcn_exp2f)
  return __builtin_amdgcn_exp2f(v);
#else
  return exp2f(v);
#endif
#else
  return exp2f(v);
#endif
}

// ---------------------------------------------------------------------------
// K1': pairs_u[b][j] = ( x_j*log2e , -Bsum_j*log2e ), Bsum exact over all k.
// grid = 64*16 (b,jc); thread = (jl = tid&63, ks = tid>>6): 1 j, 256-k slice.
// x[b] staged in LDS; k-slice reads are wave-uniform b128 broadcasts.
// ---------------------------------------------------------------------------
__global__ __launch_bounds__(256) void k1_pairs(const float* __restrict__ x,
                                                float2* __restrict__ pairs_u) {
  int jc = blockIdx.x & 15;
  int b  = blockIdx.x >> 4;
  __shared__ float xall[Dn];
  __shared__ float part[4][64];
  int tid = threadIdx.x;
  *(float4*)&xall[tid * 4] = *(const float4*)(x + b * Dn + tid * 4);
  __syncthreads();
  int jl = tid & 63, ks = tid >> 6;
  float xj = xall[jc * 64 + jl];
  const float* kp = &xall[ks * 256];
  float a0 = 0.f, a1 = 0.f, a2 = 0.f, a3 = 0.f;
#pragma unroll 8
  for (int k = 0; k < 256; k += 4) {
    float4 kv = *(const float4*)(kp + k);
    a0 += fabsf(xj - kv.x);
    a1 += fabsf(xj - kv.y);
    a2 += fabsf(xj - kv.z);
    a3 += fabsf(xj - kv.w);
  }
  part[ks][jl] = (a0 + a1) + (a2 + a3);
  __syncthreads();
  if (tid < 64) {
    float s = (part[0][tid] + part[1][tid]) + (part[2][tid] + part[3][tid]);
    float a = xall[jc * 64 + tid] * LOG2E;
    pairs_u[b * Dn + jc * 64 + tid] = make_float2(a, -s * LOG2E);
  }
}

// ---------------------------------------------------------------------------
// K1b: compact counting-sort of pairs by monotone logistic bucket of x
// (64 buckets; uneven counts fine — compact, no spills, ties harmless).
// One block per b.  Also zeroes d_out (atomics target for k4).
// ---------------------------------------------------------------------------
__global__ __launch_bounds__(256) void k1b_sort(
    const float2* __restrict__ pairs_u, float2* __restrict__ pairs_s,
    float* __restrict__ out) {
  int b = blockIdx.x;
  int tid = threadIdx.x;
  __shared__ int cnt[64], base_[64], off_[64];
  __shared__ float2 ss[Dn];
  if (tid < 64) cnt[tid] = 0;
  __syncthreads();
  float2 v[4]; int bk[4];
#pragma unroll
  for (int u = 0; u < 4; ++u) {
    v[u] = pairs_u[b * Dn + u * 256 + tid];
    // p = 1/(1+e^{-1.702 x}) = 1/(1+2^{-1.702 a}) (a = x*log2e), monotone in x
    float p = 1.f / (1.f + exp2_fast(-1.702f * v[u].x));
    int t = (int)(p * 64.f);
    bk[u] = t < 0 ? 0 : (t > 63 ? 63 : t);
    atomicAdd(&cnt[bk[u]], 1);
  }
  __syncthreads();
  if (tid < 64) {
    int c = cnt[tid], s = c;
#pragma unroll
    for (int d = 1; d < 64; d <<= 1) {
      int o = __shfl_up(s, d, 64);
      if (tid >= d) s += o;
    }
    base_[tid] = s - c;                    // exclusive prefix
    off_[tid] = 0;
  }
  __syncthreads();
#pragma unroll
  for (int u = 0; u < 4; ++u) {
    int pos = base_[bk[u]] + atomicAdd(&off_[bk[u]], 1);
    ss[pos] = v[u];
  }
  __syncthreads();
#pragma unroll
  for (int u = 0; u < 4; ++u)
    pairs_s[b * Dn + u * 256 + tid] = ss[u * 256 + tid];
  if (b == 0 && tid < 128) out[tid] = 0.f;
}

// ---------------------------------------------------------------------------
// K2: xs[b,i] = sum_j softmax_j(sc_i*x_j - Bsum_j) * x_j  (exp2 domain).
// Lane = row (64 consecutive i per block); waves own interleaved groups-of-8
// of the SORTED position space (g = 4q + w), loads wave-uniform.
// Pass1: exact max over all 1024, exact per-group maxima gm[32] in regs.
// Pass2: vote-skip groups with gm <= mAll-44 (error <= 1024*2^-44, exact SE>=1).
// grid = 64*16 = 1024 blocks of 256.
// ---------------------------------------------------------------------------
__global__ __launch_bounds__(256, 4) void k2_softsort(
    const float2* __restrict__ pairs_s, float* __restrict__ xs_out) {
  __shared__ float redM[4][64], redE[4][64], redD[4][64];
  int b  = blockIdx.x >> 4;
  int rc = blockIdx.x & 15;
  int tid = threadIdx.x;
  int w = tid >> 6, lane = tid & 63;
  int i = rc * 64 + lane;
  float sc = (float)(Dn - 1 - 2 * i);      // exact in fp32
  const float2* ps = pairs_s + b * Dn;

  float gm[32];
  float m = -3.4e38f;
#pragma unroll
  for (int q = 0; q < 32; ++q) {
    int base = (q * 4 + w) * 8;
    float g0 = -3.4e38f, g1 = -3.4e38f;
#pragma unroll
    for (int u = 0; u < 8; u += 2) {
      float2 v0 = ps[base + u];
      float2 v1 = ps[base + u + 1];
      g0 = fmaxf(g0, fmaf(sc, v0.x, v0.y));
      g1 = fmaxf(g1, fmaf(sc, v1.x, v1.y));
    }
    float g = fmaxf(g0, g1);
    gm[q] = g;
    m = fmaxf(m, g);
  }
  redM[w][lane] = m;
  __syncthreads();
  float mAll = fmaxf(fmaxf(redM[0][lane], redM[1][lane]),
                     fmaxf(redM[2][lane], redM[3][lane]));
  float thresh = mAll - 44.f;

  float se = 0.f, sd = 0.f;
#pragma unroll
  for (int q = 0; q < 32; ++q) {
    if (__any(gm[q] > thresh)) {
      int base = (q * 4 + w) * 8;
#pragma unroll
      for (int u = 0; u < 8; ++u) {
        float2 v = ps[base + u];
        float e = exp2_fast(fmaf(sc, v.x, v.y - mAll));
        se += e;
        sd = fmaf(e, v.x, sd);
      }
    }
  }
  redE[w][lane] = se;
  redD[w][lane] = sd;
  __syncthreads();
  if (tid < 64) {
    float SE = (redE[0][lane] + redE[1][lane]) + (redE[2][lane] + redE[3][lane]);
    float SD = (redD[0][lane] + redD[1][lane]) + (redD[2][lane] + redD[3][lane]);
    xs_out[b * Dn + rc * 64 + lane] = SD / SE * LN2;
  }
}

// ---------------------------------------------------------------------------
// K3/K4: h = leaky(in @ W^T + bias).  Block = 8 batches x 16 cols.
// Thread tile = 1 batch x 4 cols x K/8; grid = 512.  TAIL fuses layer 3.
// ---------------------------------------------------------------------------
template <bool TAIL>
__global__ __launch_bounds__(256) void layer_kernel(
    const float* __restrict__ in, const float* __restrict__ W,
    const float* __restrict__ bias, float* __restrict__ out,
    const float* __restrict__ W3, const float* __restrict__ b3,
    float* __restrict__ out2) {
  __shared__ float s[8][Dn + 4];
  __shared__ float red[8][16][8];
  __shared__ float r2[8][16][2];
  int bc = blockIdx.x >> 6;
  int nc = blockIdx.x & 63;
  int tid = threadIdx.x;
  const float* src = in + bc * 8 * Dn;
#pragma unroll
  for (int u = 0; u < 8; ++u) {
    int idx = (u * 256 + tid) << 2;
    *(float4*)&s[idx >> 10][idx & 1023] = *(const float4*)(src + idx);
  }
  __syncthreads();

  int bl = tid & 7;
  int nq = (tid >> 3) & 3;
  int kc = tid >> 5;
  int n0 = nc * 16 + nq * 4;
  const float* a  = &s[bl][kc * 128];
  const float* w0 = W + (size_t)(n0 + 0) * Dn + kc * 128;
  const float* w1 = W + (size_t)(n0 + 1) * Dn + kc * 128;
  const float* w2 = W + (size_t)(n0 + 2) * Dn + kc * 128;
  const float* w3 = W + (size_t)(n0 + 3) * Dn + kc * 128;
  float a0 = 0.f, a1 = 0.f, a2 = 0.f, a3 = 0.f;
#pragma unroll 4
  for (int kq = 0; kq < 32; ++kq) {
    float4 av = *(const float4*)(a + kq * 4);
    float4 b0 = *(const float4*)(w0 + kq * 4);
    float4 b1 = *(const float4*)(w1 + kq * 4);
    float4 b2 = *(const float4*)(w2 + kq * 4);
    float4 b3v = *(const float4*)(w3 + kq * 4);
    a0 = fmaf(av.x, b0.x, fmaf(av.y, b0.y, fmaf(av.z, b0.z, fmaf(av.w, b0.w, a0))));
    a1 = fmaf(av.x, b1.x, fmaf(av.y, b1.y, fmaf(av.z, b1.z, fmaf(av.w, b1.w, a1))));
    a2 = fmaf(av.x, b2.x, fmaf(av.y, b2.y, fmaf(av.z, b2.z, fmaf(av.w, b2.w, a2))));
    a3 = fmaf(av.x, b3v.x, fmaf(av.y, b3v.y, fmaf(av.z, b3v.z, fmaf(av.w, b3v.w, a3))));
  }
  red[bl][nq * 4 + 0][kc] = a0;
  red[bl][nq * 4 + 1][kc] = a1;
  red[bl][nq * 4 + 2][kc] = a2;
  red[bl][nq * 4 + 3][kc] = a3;
  __syncthreads();

  if (!TAIL) {
    if (tid < 128) {
      int bl2 = tid >> 4, nl2 = tid & 15;
      int n2 = nc * 16 + nl2;
      float hs = 0.f;
#pragma unroll
      for (int q = 0; q < 8; ++q) hs += red[bl2][nl2][q];
      float h = hs + bias[n2];
      h = h >= 0.f ? h : 0.01f * h;
      out[(bc * 8 + bl2) * Dn + n2] = h;
    }
  } else {
    if (tid < 128) {
      int bl2 = tid >> 4, nl2 = tid & 15;
      int n2 = nc * 16 + nl2;
      float hs = 0.f;
#pragma unroll
      for (int q = 0; q < 8; ++q) hs += red[bl2][nl2][q];
      float h = hs + bias[n2];
      h = h >= 0.f ? h : 0.01f * h;
      r2[bl2][nl2][0] = h * W3[n2];
      r2[bl2][nl2][1] = h * W3[Dn + n2];
    }
    __syncthreads();
    if (tid < 16) {
      int bl2 = tid >> 1, o = tid & 1;
      float t = 0.f;
#pragma unroll
      for (int q = 0; q < 16; ++q) t += r2[bl2][q][o];
      if (nc == 0) t += b3[o];
      atomicAdd(out2 + (bc * 8 + bl2) * 2 + o, t);
    }
  }
}

extern "C" void kernel_launch(void* const* d_in, const int* in_sizes, int n_in,
                              void* d_out, int out_size, void* d_ws, size_t ws_size,
                              hipStream_t stream) {
  const float* x  = (const float*)d_in[0];
  const float* W1 = (const float*)d_in[1];
  const float* b1 = (const float*)d_in[2];
  const float* W2 = (const float*)d_in[3];
  const float* b2 = (const float*)d_in[4];
  const float* W3 = (const float*)d_in[5];
  const float* b3 = (const float*)d_in[6];
  float* out = (float*)d_out;
  float* ws = (float*)d_ws;

  float2* pairs_u = (float2*)ws;                     // 64*1024 float2 = 512 KB
  float2* pairs_s = pairs_u + Bn * Dn;               // 512 KB
  float*  xs      = (float*)(pairs_s + Bn * Dn);     // 256 KB
  float*  h1      = xs + Bn * Dn;                    // 256 KB

  k1_pairs<<<Bn * 16, 256, 0, stream>>>(x, pairs_u);
  k1b_sort<<<Bn, 256, 0, stream>>>(pairs_u, pairs_s, out);
  k2_softsort<<<Bn * 16, 256, 0, stream>>>(pairs_s, xs);
  layer_kernel<false><<<512, 256, 0, stream>>>(xs, W1, b1, h1,
                                               nullptr, nullptr, nullptr);
  layer_kernel<true><<<512, 256, 0, stream>>>(h1, W2, b2, nullptr,
                                              W3, b3, out);
}